// Round 6
// baseline (311093.237 us; speedup 1.0000x reference)
//
#include <hip/hip_runtime.h>

// ============================================================================
// Persistent pipelined LSTM-with-projection, MI355X (gfx950).
//
// R13 vs R12 (305ms, spill catastrophe) / R11 (31.0ms, last good):
// R12's depth-8 pipelines needed >256 VGPR -> scratch spills (FETCH+WRITE
// 657 GB/dispatch, 10x slowdown). Same latency-cover mechanism, budgeted:
//  (1) run_half depth-4: 4 chunk loads upfront (8 named F4 = 32 VGPR),
//      issue(c+4) at line c -> ~1000cy cover vs R11's ~500cy.
//  (2) proj depth-4: straight-line 32 chunks, 4 named sets (12 F4 = 48 VGPR),
//      issue(c+4) at line c; 2 rotating flag regs loaded 2 pairs (~4 lines)
//      ahead of ballot-verify. Same FMA order -> bitwise-identical result.
//  (3) self-flag skip kept from R12 (own store precedes in program order).
// GEMM/proj register sets are phase-disjoint (compiler overlays); estimated
// peak ~160-190 VGPR. Watchdog + abort protocol unchanged (hang -> fast fail
// with counters). Flag/ring/WAR invariants line-for-line R11.
// ============================================================================

#define B_    64
#define T_    1024
#define P_    256
#define H_    1024
#define L_    4
#define G4_   4096
#define NTHR  256
#define WWIN  8                     // h ring slots (power of two)
#define HSLOT (P_ * B_)             // 16384 floats per slot, layout [b][p]

// LDS (floats): WHI 16384 | WLO 16384 | XS 4096 | ACT 1024 | ABRT 4 = 37892
#define LDS_FLOATS 37892
#define LDS_BYTES  (LDS_FLOATS * 4)

// projection arena overlays XS+ACT (both dead during proj): 4896 <= 5120
#define PA_CH  36                   // padded row: 32 j + 4
#define PA_BUF (64 * PA_CH)         // 2304 floats per act chunk buffer
#define PW_OFF (2 * PA_BUF)         // 4608: two Whr chunk buffers of 144
#define PW_BUF (4 * PA_CH)          // 144

#define ACT_FLOATS ((size_t)L_ * H_ * B_)        // 1 MB act broadcast bufs
#define WDOG_CAP 200000             // bounded polling before abort

struct alignas(16) F4 { float f[4]; };
typedef __attribute__((ext_vector_type(8))) short s8v;   // 8 bf16 (4 VGPRs)
typedef __attribute__((ext_vector_type(4))) float f4v;   // MFMA C/D

// ---- cross-WG data movement: compiler-tracked agent-scope accesses ---------
__device__ __forceinline__ void lda2(const float* p, float& a, float& b) {
  union { double d; float f[2]; } u;
  u.d = __hip_atomic_load((const double*)p, __ATOMIC_RELAXED,
                          __HIP_MEMORY_SCOPE_AGENT);
  a = u.f[0]; b = u.f[1];
}
__device__ __forceinline__ void sta2(float* p, float a, float b) {
  union { double d; float f[2]; } u;
  u.f[0] = a; u.f[1] = b;
  __hip_atomic_store((double*)p, u.d, __ATOMIC_RELAXED,
                     __HIP_MEMORY_SCOPE_AGENT);
}
__device__ __forceinline__ void sta(float* p, float v) {
  __hip_atomic_store(p, v, __ATOMIC_RELAXED, __HIP_MEMORY_SCOPE_AGENT);
}
__device__ __forceinline__ void drain_vm() {   // release: drain own stores
  asm volatile("s_waitcnt vmcnt(0)" ::: "memory");
}
// Hot-loop barrier: LDS visibility only -- does NOT drain vmcnt, so global
// prefetches survive. Compiler inserts vmcnt waits before each USE.
__device__ __forceinline__ void bar_lds() {
  asm volatile("s_waitcnt lgkmcnt(0)\n\ts_barrier" ::: "memory");
}

__device__ __forceinline__ float fsig(float x) {
  float e = __expf(-x);                        // saturation-safe
  return __builtin_amdgcn_rcpf(1.0f + e);
}
__device__ __forceinline__ float ftanh(float x) {
  float ax = fabsf(x);
  float e  = __expf(-2.0f * ax);               // in (0,1] -> no overflow/NaN
  float r  = (1.0f - e) * __builtin_amdgcn_rcpf(1.0f + e);
  return copysignf(r, x);
}
// ---- bf16 split helpers (round-to-nearest-even) ----------------------------
__device__ __forceinline__ ushort bf16_rne(float f) {
  uint u = __float_as_uint(f);
  uint r = u + 0x7FFFu + ((u >> 16) & 1u);
  return (ushort)(r >> 16);
}
__device__ __forceinline__ float bf16_to_f(ushort h) {
  return __uint_as_float(((uint)h) << 16);
}
// wave 0 polls 64 flags; others park at the barrier. Lane == self substitutes
// satisfied (own store precedes in program order). Returns nonzero on abort.
__device__ __forceinline__ int wait1(int* f, int tid, int target, int* abrt,
                                     int self) {
  if (tid < 64) {
    int it = 0;
    while (true) {
      int v = (tid == self) ? 0x7fffffff
            : __hip_atomic_load(&f[tid], __ATOMIC_RELAXED, __HIP_MEMORY_SCOPE_AGENT);
      if (__ballot(v < target) == 0ull) break;
      if (++it > WDOG_CAP || *abrt) { if (tid == 0) *abrt = 1; break; }
      __builtin_amdgcn_s_sleep(2);
    }
  }
  __syncthreads();
  asm volatile("" ::: "memory");   // no hoisting data loads above the wait
  return *abrt;                    // LDS, uniform across WG
}

extern "C" __global__ void __launch_bounds__(NTHR, 1)
lstm_persistent(const float* __restrict__ y,
                const float* __restrict__ Wih,
                const float* __restrict__ Whh,
                const float* __restrict__ bih,
                const float* __restrict__ bhh,
                const float* __restrict__ Whr,
                const int*   __restrict__ mslp,
                float*       __restrict__ out,
                float*       __restrict__ hbuf,
                float*       __restrict__ actg,
                int*         __restrict__ hflag,
                int*         __restrict__ pflag)
{
  extern __shared__ float lds[];
  ushort* WHI  = (ushort*)lds;          // frag-linear: [(kt*4+g)*64+m] x 8 bf16
  ushort* WLO  = WHI + 32768;
  ushort* XS   = WLO + 32768;           // 2 bufs x (256 hi + 256 lo) frags
  float*  ACTf = lds + 36864;           // [16 cells][64 b]
  float*  PRJ  = lds + 32768;           // proj arena over XS+ACT (4896 floats)
  int*    ABRT = (int*)(lds + 37888);   // watchdog abort word

  const int bid = blockIdx.x;
  const int l   = (bid & 7) >> 1;       // layer on XCD pair {2l,2l+1}
  const int w   = ((bid & 1)) + 2 * (bid >> 3);   // 0..63, bijective
  const int J0  = w * 16;
  const int tid = threadIdx.x;
  const int msl = mslp[0];

  if (tid == 0) *ABRT = 0;

  // ---- one-time: gate weights -> bf16 (hi,lo) frag-linear LDS -------------
  {
    const float* wih_l = Wih + (size_t)l * G4_ * P_;
    const float* whh_l = Whh + (size_t)l * G4_ * P_;
    for (int e = tid; e < 4096; e += NTHR) {
      int m  = e & 63;
      int g  = (e >> 6) & 3;
      int kt = e >> 8;
      int grow = (m & 3) * H_ + J0 + (m >> 2);    // torch gate order i,f,g,o
      int k = kt * 32 + g * 8;
      const float* src = (k < 256) ? (wih_l + (size_t)grow * P_ + k)
                                   : (whh_l + (size_t)grow * P_ + (k - 256));
      F4 aa = *(const F4*)src;
      F4 bb = *(const F4*)(src + 4);
      float xs8[8] = {aa.f[0], aa.f[1], aa.f[2], aa.f[3],
                      bb.f[0], bb.f[1], bb.f[2], bb.f[3]};
      s8v h8, l8;
#pragma unroll
      for (int i = 0; i < 8; ++i) {
        ushort hi = bf16_rne(xs8[i]);
        ushort lo = bf16_rne(xs8[i] - bf16_to_f(hi));
        h8[i] = (short)hi; l8[i] = (short)lo;
      }
      ((s8v*)WHI)[e] = h8;
      ((s8v*)WLO)[e] = l8;
    }
  }
  __syncthreads();

  // ---- thread mappings ----------------------------------------------------
  const int w4   = tid >> 6;            // wave 0..3 = M-stripe (16 gate rows)
  const int lane = tid & 63;
  const int gq   = lane >> 4;           // k-group of A/B fragment
  const int lm   = lane & 15;           // A row-in-stripe / D column (b)
  const int aix  = 16 * w4 + lm;        // A fragment row index 0..63
  const int cellj = 4 * w4 + gq;        // my cell 0..15 (from D layout)
  // staging: thread -> (b, k-octet)
  const int sb = tid >> 2;              // b 0..63
  const int sg = tid & 3;               // k-group 0..3 (k0 = 8*sg)
  // act repack / proj staging:
  const int jqr = tid >> 6, b_r = tid & 63;
  // proj compute:
  const int b_p = (w4 << 4) | (tid & 15);
  const int pw  = (tid >> 4) & 3;
  // proj Whr staging (threads 0..31 only):
  const int pws = tid >> 3, jqlw = tid & 7;   // valid when tid < 32

  float* hsrc = hbuf + (size_t)l * (WWIN * HSLOT);
  const float* hprv = (l > 0) ? (hbuf + (size_t)(l - 1) * (WWIN * HSLOT)) : hbuf;
  float* AGf = actg + (size_t)l * H_ * B_;   // [jq 0..255][b 0..63] of 4 floats

  float biasr[4];
#pragma unroll
  for (int gg = 0; gg < 4; ++gg) {
    int grow = gg * H_ + J0 + cellj;
    biasr[gg] = bih[l * G4_ + grow] + bhh[l * G4_ + grow];
  }

  float cst[4] = {0.f, 0.f, 0.f, 0.f};       // c-state: my cell at 4 b's
  f4v acc[4];                                // gate accum, lives across tail

  // ---- GEMM machinery -----------------------------------------------------
  auto gemm_chunk = [&](int kt, int par) {
    const s8v* WHIv = (const s8v*)WHI;
    const s8v* WLOv = (const s8v*)WLO;
    s8v ahi = WHIv[(kt * 4 + gq) * 64 + aix];
    s8v alo = WLOv[(kt * 4 + gq) * 64 + aix];
    const s8v* XB = (const s8v*)XS + par * 512;
    const int bbase = gq * 64 + lm;
#pragma unroll
    for (int nt = 0; nt < 4; ++nt) {
      s8v bhi = XB[bbase + nt * 16];
      s8v blo = XB[256 + bbase + nt * 16];
      acc[nt] = __builtin_amdgcn_mfma_f32_16x16x32_bf16(ahi, bhi, acc[nt], 0, 0, 0);
      acc[nt] = __builtin_amdgcn_mfma_f32_16x16x32_bf16(ahi, blo, acc[nt], 0, 0, 0);
      acc[nt] = __builtin_amdgcn_mfma_f32_16x16x32_bf16(alo, bhi, acc[nt], 0, 0, 0);
    }
  };
  auto ring_issue = [&](const float* src, int cc, F4& u, F4& v) {
    const float* p = src + (size_t)sb * P_ + ((cc & 7) << 5) + 8 * sg;
    lda2(p + 0, u.f[0], u.f[1]);
    lda2(p + 2, u.f[2], u.f[3]);
    lda2(p + 4, v.f[0], v.f[1]);
    lda2(p + 6, v.f[2], v.f[3]);
  };
  auto commit_x = [&](int par, const F4& u, const F4& v) {
    s8v h8, l8;
#pragma unroll
    for (int i = 0; i < 4; ++i) {
      ushort hu = bf16_rne(u.f[i]);
      ushort lu = bf16_rne(u.f[i] - bf16_to_f(hu));
      ushort hv = bf16_rne(v.f[i]);
      ushort lv = bf16_rne(v.f[i] - bf16_to_f(hv));
      h8[i]     = (short)hu; l8[i]     = (short)lu;
      h8[i + 4] = (short)hv; l8[i + 4] = (short)lv;
    }
    s8v* XB = (s8v*)XS + par * 512;
    XB[sg * 64 + sb]       = h8;
    XB[256 + sg * 64 + sb] = l8;
  };
  // depth-4 pipelined half: 4 chunk loads upfront, issue(c+4) at line c
  auto run_half = [&](auto&& ISSUE, int c0) {
    F4 u0,v0,u1,v1,u2,v2,u3,v3;
    ISSUE(c0+0,u0,v0); ISSUE(c0+1,u1,v1); ISSUE(c0+2,u2,v2); ISSUE(c0+3,u3,v3);
    commit_x(0, u0, v0);
    bar_lds();
    ISSUE(c0+4,u0,v0); gemm_chunk(c0+0, 0); commit_x(1, u1, v1); bar_lds();
    ISSUE(c0+5,u1,v1); gemm_chunk(c0+1, 1); commit_x(0, u2, v2); bar_lds();
    ISSUE(c0+6,u2,v2); gemm_chunk(c0+2, 0); commit_x(1, u3, v3); bar_lds();
    ISSUE(c0+7,u3,v3); gemm_chunk(c0+3, 1); commit_x(0, u0, v0); bar_lds();
    gemm_chunk(c0+4, 0); commit_x(1, u1, v1); bar_lds();
    gemm_chunk(c0+5, 1); commit_x(0, u2, v2); bar_lds();
    gemm_chunk(c0+6, 0); commit_x(1, u3, v3); bar_lds();
    gemm_chunk(c0+7, 1);
    // no trailing bar: following phases touch disjoint LDS or sync first
  };
  auto do_xhalf = [&](int tt) {
    f4v z = {0.f, 0.f, 0.f, 0.f};
#pragma unroll
    for (int nt = 0; nt < 4; ++nt) acc[nt] = z;
    if (l == 0) {
      auto yi = [&](int cc, F4& u, F4& v) {
        const float* p = y + ((size_t)sb * T_ + tt) * P_ + ((cc & 7) << 5) + 8 * sg;
        u = *(const F4*)p;
        v = *(const F4*)(p + 4);
      };
      run_half(yi, 0);
    } else {
      const float* xp = hprv + (size_t)(tt & (WWIN - 1)) * HSLOT;
      auto xi = [&](int cc, F4& u, F4& v) { ring_issue(xp, cc, u, v); };
      run_half(xi, 0);
    }
  };

  // ---- prologue: x-half(0) ------------------------------------------------
  if (l > 0) { if (wait1(hflag + (l - 1) * 64, tid, 0, ABRT, -1)) return; }
  do_xhalf(0);

  const int cbase = w >> 1;              // own proj chunk (rotation start)

  for (int t = 0; t < T_; ++t) {
    if (*ABRT) return;

    // ---- h-half (recurrent critical path; k-tiles 8..15 = Whh) -----------
    if (t > 0) {
      if (wait1(hflag + l * 64, tid, t - 1, ABRT, w)) return;
      const float* hp = hsrc + (size_t)((t - 1) & (WWIN - 1)) * HSLOT;
      auto hi_ = [&](int cc, F4& u, F4& v) { ring_issue(hp, cc, u, v); };
      run_half(hi_, 8);
    }

    // ---- activations + cell update (D: col=lane&15, row=4*gq+reg) --------
#pragma unroll
    for (int nt = 0; nt < 4; ++nt) {
      float vi = acc[nt][0] + biasr[0];
      float vf = acc[nt][1] + biasr[1];
      float vg = acc[nt][2] + biasr[2];
      float vo = acc[nt][3] + biasr[3];
      float ig = fsig(vi), fg = fsig(vf), g2 = ftanh(vg), og = fsig(vo);
      float cn = fmaf(fg, cst[nt], ig * g2);
      cst[nt] = cn;
      ACTf[cellj * 64 + nt * 16 + lm] = og * ftanh(cn);
    }
    bar_lds();

    // ---- broadcast acts: LDS -> global [jq][b][4], dwordx2 agent stores --
    {
      float a0 = ACTf[(4 * jqr + 0) * 64 + b_r];
      float a1 = ACTf[(4 * jqr + 1) * 64 + b_r];
      float a2 = ACTf[(4 * jqr + 2) * 64 + b_r];
      float a3 = ACTf[(4 * jqr + 3) * 64 + b_r];
      float* dst = AGf + ((size_t)(4 * w + jqr) * 64 + b_r) * 4;
      sta2(dst + 0, a0, a1);
      sta2(dst + 2, a2, a3);
    }
    drain_vm();          // release: own stores complete at coherence point
    __syncthreads();     // all waves drained
    if (tid == 0)
      __hip_atomic_store(&pflag[l * 64 + w], t, __ATOMIC_RELAXED, __HIP_MEMORY_SCOPE_AGENT);

    // ---- projection: depth-4 pipeline, progressive register-gated --------
    int* pfl = pflag + l * 64;
    auto achunk = [&](int c) { return (cbase + c) & 31; };
    auto fld = [&](int p) {
      int idx = (2 * achunk(2 * p) + (lane & 3)) & 63;
      return (idx == w) ? 0x7fffffff
           : __hip_atomic_load(&pfl[idx], __ATOMIC_RELAXED, __HIP_MEMORY_SCOPE_AGENT);
    };
    auto fver = [&](int& fv, int p) {
      int it = 0;
      while (__ballot(fv < t) != 0ull) {
        if (++it > WDOG_CAP || *ABRT) { if (tid == 0) *ABRT = 1; break; }
        __builtin_amdgcn_s_sleep(2);
        fv = fld(p);
      }
      asm volatile("" ::: "memory");   // gated loads must not hoist above
    };
    auto proj_issue = [&](int ch, F4& lo, F4& hi, F4& wv) {
      const float* a0 = AGf + ((size_t)(8 * ch + 2 * jqr) * 64 + b_r) * 4;
      lda2(a0 + 0,   lo.f[0], lo.f[1]);
      lda2(a0 + 2,   lo.f[2], lo.f[3]);
      lda2(a0 + 256, hi.f[0], hi.f[1]);
      lda2(a0 + 258, hi.f[2], hi.f[3]);
      if (tid < 32)      // Whr is read-only input: plain cached load
        wv = *(const F4*)(Whr + ((size_t)(l * P_ + 4 * w + pws)) * H_
                          + 32 * ch + 4 * jqlw);
    };
    auto proj_commit = [&](int bufi, F4& lo, F4& hi, F4& wv) {
      float* ab = PRJ + bufi * PA_BUF;
      *(F4*)&ab[b_r * PA_CH + 8 * jqr]     = lo;
      *(F4*)&ab[b_r * PA_CH + 8 * jqr + 4] = hi;
      if (tid < 32)
        *(F4*)&(PRJ + PW_OFF + bufi * PW_BUF)[pws * PA_CH + 4 * jqlw] = wv;
    };
    float s = 0.f;
    auto proj_comp = [&](int bufi) {
      const float* ab = PRJ + bufi * PA_BUF + b_p * PA_CH;
      const float* wb = PRJ + PW_OFF + bufi * PW_BUF + pw * PA_CH;
#pragma unroll
      for (int jj = 0; jj < 8; ++jj) {
        F4 a  = *(const F4*)&ab[4 * jj];
        F4 wv = *(const F4*)&wb[4 * jj];
        s = fmaf(a.f[0], wv.f[0], s);
        s = fmaf(a.f[1], wv.f[1], s);
        s = fmaf(a.f[2], wv.f[2], s);
        s = fmaf(a.f[3], wv.f[3], s);
      }
    };

    {
      // prologue: verify pairs 0,1; stage flags for pairs 2,3; 4 issues
      int f0 = fld(0); fver(f0, 0);
      int f1 = fld(1); fver(f1, 1);
      int fA = fld(2), fB = fld(3);
      F4 L0,H0,W0, L1,H1,W1, L2,H2,W2, L3,H3,W3;
      proj_issue(achunk(0), L0, H0, W0);
      proj_issue(achunk(1), L1, H1, W1);
      proj_issue(achunk(2), L2, H2, W2);
      proj_issue(achunk(3), L3, H3, W3);
      proj_commit(0, L0, H0, W0);
      bar_lds();
      // line c: [even c: fver pair (c+4)/2] issue(c+4 -> set c&3);
      //         comp(buf c&1); commit(c+1 -> set (c+1)&3, buf (c+1)&1); bar
      fver(fA,2); proj_issue(achunk(4),  L0,H0,W0); proj_comp(0); proj_commit(1, L1,H1,W1); bar_lds(); fA = fld(4);
                  proj_issue(achunk(5),  L1,H1,W1); proj_comp(1); proj_commit(0, L2,H2,W2); bar_lds();
      fver(fB,3); proj_issue(achunk(6),  L2,H2,W2); proj_comp(0); proj_commit(1, L3,H3,W3); bar_lds(); fB = fld(5);
                  proj_issue(achunk(7),  L3,H3,W3); proj_comp(1); proj_commit(0, L0,H0,W0); bar_lds();
      fver(fA,4); proj_issue(achunk(8),  L0,H0,W0); proj_comp(0); proj_commit(1, L1,H1,W1); bar_lds(); fA = fld(6);
                  proj_issue(achunk(9),  L1,H1,W1); proj_comp(1); proj_commit(0, L2,H2,W2); bar_lds();
      fver(fB,5); proj_issue(achunk(10), L2,H2,W2); proj_comp(0); proj_commit(1, L3,H3,W3); bar_lds(); fB = fld(7);
                  proj_issue(achunk(11), L3,H3,W3); proj_comp(1); proj_commit(0, L0,H0,W0); bar_lds();
      fver(fA,6); proj_issue(achunk(12), L0,H0,W0); proj_comp(0); proj_commit(1, L1,H1,W1); bar_lds(); fA = fld(8);
                  proj_issue(achunk(13), L1,H1,W1); proj_comp(1); proj_commit(0, L2,H2,W2); bar_lds();
      fver(fB,7); proj_issue(achunk(14), L2,H2,W2); proj_comp(0); proj_commit(1, L3,H3,W3); bar_lds(); fB = fld(9);
                  proj_issue(achunk(15), L3,H3,W3); proj_comp(1); proj_commit(0, L0,H0,W0); bar_lds();
      fver(fA,8); proj_issue(achunk(16), L0,H0,W0); proj_comp(0); proj_commit(1, L1,H1,W1); bar_lds(); fA = fld(10);
                  proj_issue(achunk(17), L1,H1,W1); proj_comp(1); proj_commit(0, L2,H2,W2); bar_lds();
      fver(fB,9); proj_issue(achunk(18), L2,H2,W2); proj_comp(0); proj_commit(1, L3,H3,W3); bar_lds(); fB = fld(11);
                  proj_issue(achunk(19), L3,H3,W3); proj_comp(1); proj_commit(0, L0,H0,W0); bar_lds();
      fver(fA,10); proj_issue(achunk(20), L0,H0,W0); proj_comp(0); proj_commit(1, L1,H1,W1); bar_lds(); fA = fld(12);
                   proj_issue(achunk(21), L1,H1,W1); proj_comp(1); proj_commit(0, L2,H2,W2); bar_lds();
      fver(fB,11); proj_issue(achunk(22), L2,H2,W2); proj_comp(0); proj_commit(1, L3,H3,W3); bar_lds(); fB = fld(13);
                   proj_issue(achunk(23), L3,H3,W3); proj_comp(1); proj_commit(0, L0,H0,W0); bar_lds();
      fver(fA,12); proj_issue(achunk(24), L0,H0,W0); proj_comp(0); proj_commit(1, L1,H1,W1); bar_lds(); fA = fld(14);
                   proj_issue(achunk(25), L1,H1,W1); proj_comp(1); proj_commit(0, L2,H2,W2); bar_lds();
      fver(fB,13); proj_issue(achunk(26), L2,H2,W2); proj_comp(0); proj_commit(1, L3,H3,W3); bar_lds(); fB = fld(15);
                   proj_issue(achunk(27), L3,H3,W3); proj_comp(1); proj_commit(0, L0,H0,W0); bar_lds();
      fver(fA,14); proj_issue(achunk(28), L0,H0,W0); proj_comp(0); proj_commit(1, L1,H1,W1); bar_lds();
                   proj_issue(achunk(29), L1,H1,W1); proj_comp(1); proj_commit(0, L2,H2,W2); bar_lds();
      fver(fB,15); proj_issue(achunk(30), L2,H2,W2); proj_comp(0); proj_commit(1, L3,H3,W3); bar_lds();
                   proj_issue(achunk(31), L3,H3,W3); proj_comp(1); proj_commit(0, L0,H0,W0); bar_lds();
                   proj_comp(0); proj_commit(1, L1,H1,W1); bar_lds();
                   proj_comp(1); proj_commit(0, L2,H2,W2); bar_lds();
                   proj_comp(0); proj_commit(1, L3,H3,W3); bar_lds();
                   proj_comp(1);
    }

    // ---- emit h (ring [b][p], agent store) + output ----------------------
    if (l < 3) {                         // ring back-pressure
      if (wait1(hflag + (l + 1) * 64, tid, t - WWIN, ABRT, -1)) return;
    }
    sta(hsrc + (size_t)(t & (WWIN - 1)) * HSLOT + (size_t)b_p * P_ + (4 * w + pw), s);
    if (l == 3 && t >= msl)
      out[((size_t)b_p * (T_ - msl) + (t - msl)) * P_ + 4 * w + pw] = s;
    drain_vm();          // release h
    __syncthreads();
    if (tid == 0)
      __hip_atomic_store(&hflag[l * 64 + w], t, __ATOMIC_RELAXED, __HIP_MEMORY_SCOPE_AGENT);

    // ---- tail: x-half(t+1) off the critical cycle ------------------------
    if (t + 1 < T_) {
      if (l > 0) { if (wait1(hflag + (l - 1) * 64, tid, t + 1, ABRT, -1)) return; }
      do_xhalf(t + 1);
    }
  }
}

extern "C" void kernel_launch(void* const* d_in, const int* in_sizes, int n_in,
                              void* d_out, int out_size, void* d_ws, size_t ws_size,
                              hipStream_t stream) {
  const float* y   = (const float*)d_in[0];
  const float* Wih = (const float*)d_in[1];
  const float* Whh = (const float*)d_in[2];
  const float* bih = (const float*)d_in[3];
  const float* bhh = (const float*)d_in[4];
  const float* Whr = (const float*)d_in[5];
  const int*   msl = (const int*)d_in[6];
  float* out = (float*)d_out;

  // ws: [flags 4KB][act broadcast 1MB][h ring 2MB]  (~3 MB total)
  char*  ws    = (char*)d_ws;
  int*   flags = (int*)ws;
  float* actg  = (float*)(ws + 4096);
  float* hbuf  = (float*)(ws + 4096 + ACT_FLOATS * sizeof(float));

  hipMemsetAsync(flags, 0xFF, 4096, stream);   // epoch counters start at -1

  hipFuncSetAttribute(reinterpret_cast<const void*>(&lstm_persistent),
                      hipFuncAttributeMaxDynamicSharedMemorySize, LDS_BYTES);

  lstm_persistent<<<dim3(L_ * 64), dim3(NTHR), LDS_BYTES, stream>>>(
      y, Wih, Whh, bih, bhh, Whr, msl, out,
      hbuf, actg, flags /*hflag*/, flags + 256 /*pflag*/);
}

// Round 7
// 30954.980 us; speedup vs baseline: 10.0499x; 10.0499x over previous
//
#include <hip/hip_runtime.h>

// ============================================================================
// Persistent pipelined LSTM-with-projection, MI355X (gfx950).
//
// R14 vs R13 (305ms, still spilling) / R11 (31.0ms, last good):
// R12/R13 spill root-cause: STRAIGHT-LINED proj let the scheduler hoist all
// 32 plain Whr F4 loads (~128 VGPR) to the phase top -> 256 VGPR + scratch.
// Fix: depth-4 proj in ROLLED form (#pragma unroll 1): 4 chunks/iteration,
// 4 named register sets with static rotation returning to the same names at
// the back-edge; issues exactly 4 chunks (~1400cy) ahead; 2+2 named flag
// regs (verify now / staged 1 iter ahead). Loop back-edge bounds hoisting to
// one iteration. GEMM run_half reverted to R11's exact depth-2 (known-good
// 124 VGPR). Self-flag skip kept. All other structure == R11/R13.
// ============================================================================

#define B_    64
#define T_    1024
#define P_    256
#define H_    1024
#define L_    4
#define G4_   4096
#define NTHR  256
#define WWIN  8                     // h ring slots (power of two)
#define HSLOT (P_ * B_)             // 16384 floats per slot, layout [b][p]

// LDS (floats): WHI 16384 | WLO 16384 | XS 4096 | ACT 1024 | ABRT 4 = 37892
#define LDS_FLOATS 37892
#define LDS_BYTES  (LDS_FLOATS * 4)

// projection arena overlays XS+ACT (both dead during proj): 4896 <= 5120
#define PA_CH  36                   // padded row: 32 j + 4
#define PA_BUF (64 * PA_CH)         // 2304 floats per act chunk buffer
#define PW_OFF (2 * PA_BUF)         // 4608: two Whr chunk buffers of 144
#define PW_BUF (4 * PA_CH)          // 144

#define ACT_FLOATS ((size_t)L_ * H_ * B_)        // 1 MB act broadcast bufs
#define WDOG_CAP 200000             // bounded polling before abort

struct alignas(16) F4 { float f[4]; };
typedef __attribute__((ext_vector_type(8))) short s8v;   // 8 bf16 (4 VGPRs)
typedef __attribute__((ext_vector_type(4))) float f4v;   // MFMA C/D

// ---- cross-WG data movement: compiler-tracked agent-scope accesses ---------
__device__ __forceinline__ void lda2(const float* p, float& a, float& b) {
  union { double d; float f[2]; } u;
  u.d = __hip_atomic_load((const double*)p, __ATOMIC_RELAXED,
                          __HIP_MEMORY_SCOPE_AGENT);
  a = u.f[0]; b = u.f[1];
}
__device__ __forceinline__ void sta2(float* p, float a, float b) {
  union { double d; float f[2]; } u;
  u.f[0] = a; u.f[1] = b;
  __hip_atomic_store((double*)p, u.d, __ATOMIC_RELAXED,
                     __HIP_MEMORY_SCOPE_AGENT);
}
__device__ __forceinline__ void sta(float* p, float v) {
  __hip_atomic_store(p, v, __ATOMIC_RELAXED, __HIP_MEMORY_SCOPE_AGENT);
}
__device__ __forceinline__ void drain_vm() {   // release: drain own stores
  asm volatile("s_waitcnt vmcnt(0)" ::: "memory");
}
// Hot-loop barrier: LDS visibility only -- does NOT drain vmcnt, so global
// prefetches survive. Compiler inserts vmcnt waits before each USE.
__device__ __forceinline__ void bar_lds() {
  asm volatile("s_waitcnt lgkmcnt(0)\n\ts_barrier" ::: "memory");
}

__device__ __forceinline__ float fsig(float x) {
  float e = __expf(-x);                        // saturation-safe
  return __builtin_amdgcn_rcpf(1.0f + e);
}
__device__ __forceinline__ float ftanh(float x) {
  float ax = fabsf(x);
  float e  = __expf(-2.0f * ax);               // in (0,1] -> no overflow/NaN
  float r  = (1.0f - e) * __builtin_amdgcn_rcpf(1.0f + e);
  return copysignf(r, x);
}
// ---- bf16 split helpers (round-to-nearest-even) ----------------------------
__device__ __forceinline__ ushort bf16_rne(float f) {
  uint u = __float_as_uint(f);
  uint r = u + 0x7FFFu + ((u >> 16) & 1u);
  return (ushort)(r >> 16);
}
__device__ __forceinline__ float bf16_to_f(ushort h) {
  return __uint_as_float(((uint)h) << 16);
}
// wave 0 polls 64 flags; others park at the barrier. Lane == self substitutes
// satisfied (own store precedes in program order). Returns nonzero on abort.
__device__ __forceinline__ int wait1(int* f, int tid, int target, int* abrt,
                                     int self) {
  if (tid < 64) {
    int it = 0;
    while (true) {
      int v = (tid == self) ? 0x7fffffff
            : __hip_atomic_load(&f[tid], __ATOMIC_RELAXED, __HIP_MEMORY_SCOPE_AGENT);
      if (__ballot(v < target) == 0ull) break;
      if (++it > WDOG_CAP || *abrt) { if (tid == 0) *abrt = 1; break; }
      __builtin_amdgcn_s_sleep(2);
    }
  }
  __syncthreads();
  asm volatile("" ::: "memory");   // no hoisting data loads above the wait
  return *abrt;                    // LDS, uniform across WG
}

extern "C" __global__ void __launch_bounds__(NTHR, 1)
lstm_persistent(const float* __restrict__ y,
                const float* __restrict__ Wih,
                const float* __restrict__ Whh,
                const float* __restrict__ bih,
                const float* __restrict__ bhh,
                const float* __restrict__ Whr,
                const int*   __restrict__ mslp,
                float*       __restrict__ out,
                float*       __restrict__ hbuf,
                float*       __restrict__ actg,
                int*         __restrict__ hflag,
                int*         __restrict__ pflag)
{
  extern __shared__ float lds[];
  ushort* WHI  = (ushort*)lds;          // frag-linear: [(kt*4+g)*64+m] x 8 bf16
  ushort* WLO  = WHI + 32768;
  ushort* XS   = WLO + 32768;           // 2 bufs x (256 hi + 256 lo) frags
  float*  ACTf = lds + 36864;           // [16 cells][64 b]
  float*  PRJ  = lds + 32768;           // proj arena over XS+ACT (4896 floats)
  int*    ABRT = (int*)(lds + 37888);   // watchdog abort word

  const int bid = blockIdx.x;
  const int l   = (bid & 7) >> 1;       // layer on XCD pair {2l,2l+1}
  const int w   = ((bid & 1)) + 2 * (bid >> 3);   // 0..63, bijective
  const int J0  = w * 16;
  const int tid = threadIdx.x;
  const int msl = mslp[0];

  if (tid == 0) *ABRT = 0;

  // ---- one-time: gate weights -> bf16 (hi,lo) frag-linear LDS -------------
  {
    const float* wih_l = Wih + (size_t)l * G4_ * P_;
    const float* whh_l = Whh + (size_t)l * G4_ * P_;
    for (int e = tid; e < 4096; e += NTHR) {
      int m  = e & 63;
      int g  = (e >> 6) & 3;
      int kt = e >> 8;
      int grow = (m & 3) * H_ + J0 + (m >> 2);    // torch gate order i,f,g,o
      int k = kt * 32 + g * 8;
      const float* src = (k < 256) ? (wih_l + (size_t)grow * P_ + k)
                                   : (whh_l + (size_t)grow * P_ + (k - 256));
      F4 aa = *(const F4*)src;
      F4 bb = *(const F4*)(src + 4);
      float xs8[8] = {aa.f[0], aa.f[1], aa.f[2], aa.f[3],
                      bb.f[0], bb.f[1], bb.f[2], bb.f[3]};
      s8v h8, l8;
#pragma unroll
      for (int i = 0; i < 8; ++i) {
        ushort hi = bf16_rne(xs8[i]);
        ushort lo = bf16_rne(xs8[i] - bf16_to_f(hi));
        h8[i] = (short)hi; l8[i] = (short)lo;
      }
      ((s8v*)WHI)[e] = h8;
      ((s8v*)WLO)[e] = l8;
    }
  }
  __syncthreads();

  // ---- thread mappings ----------------------------------------------------
  const int w4   = tid >> 6;            // wave 0..3 = M-stripe (16 gate rows)
  const int lane = tid & 63;
  const int gq   = lane >> 4;           // k-group of A/B fragment
  const int lm   = lane & 15;           // A row-in-stripe / D column (b)
  const int aix  = 16 * w4 + lm;        // A fragment row index 0..63
  const int cellj = 4 * w4 + gq;        // my cell 0..15 (from D layout)
  // staging: thread -> (b, k-octet)
  const int sb = tid >> 2;              // b 0..63
  const int sg = tid & 3;               // k-group 0..3 (k0 = 8*sg)
  // act repack / proj staging:
  const int jqr = tid >> 6, b_r = tid & 63;
  // proj compute:
  const int b_p = (w4 << 4) | (tid & 15);
  const int pw  = (tid >> 4) & 3;
  // proj Whr staging (threads 0..31 only):
  const int pws = tid >> 3, jqlw = tid & 7;   // valid when tid < 32

  float* hsrc = hbuf + (size_t)l * (WWIN * HSLOT);
  const float* hprv = (l > 0) ? (hbuf + (size_t)(l - 1) * (WWIN * HSLOT)) : hbuf;
  float* AGf = actg + (size_t)l * H_ * B_;   // [jq 0..255][b 0..63] of 4 floats

  float biasr[4];
#pragma unroll
  for (int gg = 0; gg < 4; ++gg) {
    int grow = gg * H_ + J0 + cellj;
    biasr[gg] = bih[l * G4_ + grow] + bhh[l * G4_ + grow];
  }

  float cst[4] = {0.f, 0.f, 0.f, 0.f};       // c-state: my cell at 4 b's
  f4v acc[4];                                // gate accum, lives across tail

  // ---- GEMM machinery (R11 depth-2, known-good) ---------------------------
  auto gemm_chunk = [&](int kt, int par) {
    const s8v* WHIv = (const s8v*)WHI;
    const s8v* WLOv = (const s8v*)WLO;
    s8v ahi = WHIv[(kt * 4 + gq) * 64 + aix];
    s8v alo = WLOv[(kt * 4 + gq) * 64 + aix];
    const s8v* XB = (const s8v*)XS + par * 512;
    const int bbase = gq * 64 + lm;
#pragma unroll
    for (int nt = 0; nt < 4; ++nt) {
      s8v bhi = XB[bbase + nt * 16];
      s8v blo = XB[256 + bbase + nt * 16];
      acc[nt] = __builtin_amdgcn_mfma_f32_16x16x32_bf16(ahi, bhi, acc[nt], 0, 0, 0);
      acc[nt] = __builtin_amdgcn_mfma_f32_16x16x32_bf16(ahi, blo, acc[nt], 0, 0, 0);
      acc[nt] = __builtin_amdgcn_mfma_f32_16x16x32_bf16(alo, bhi, acc[nt], 0, 0, 0);
    }
  };
  auto ring_issue = [&](const float* src, int cc, F4& u, F4& v) {
    const float* p = src + (size_t)sb * P_ + ((cc & 7) << 5) + 8 * sg;
    lda2(p + 0, u.f[0], u.f[1]);
    lda2(p + 2, u.f[2], u.f[3]);
    lda2(p + 4, v.f[0], v.f[1]);
    lda2(p + 6, v.f[2], v.f[3]);
  };
  auto commit_x = [&](int par, const F4& u, const F4& v) {
    s8v h8, l8;
#pragma unroll
    for (int i = 0; i < 4; ++i) {
      ushort hu = bf16_rne(u.f[i]);
      ushort lu = bf16_rne(u.f[i] - bf16_to_f(hu));
      ushort hv = bf16_rne(v.f[i]);
      ushort lv = bf16_rne(v.f[i] - bf16_to_f(hv));
      h8[i]     = (short)hu; l8[i]     = (short)lu;
      h8[i + 4] = (short)hv; l8[i + 4] = (short)lv;
    }
    s8v* XB = (s8v*)XS + par * 512;
    XB[sg * 64 + sb]       = h8;
    XB[256 + sg * 64 + sb] = l8;
  };
  auto run_half = [&](auto&& ISSUE, int c0) {
    F4 Au, Av, Bu, Bv;
    ISSUE(c0 + 0, Au, Av);
    ISSUE(c0 + 1, Bu, Bv);
    commit_x(0, Au, Av);
    bar_lds();
#pragma unroll
    for (int cc = 0; cc < 8; cc += 2) {
      if (cc + 2 < 8) ISSUE(c0 + cc + 2, Au, Av);
      gemm_chunk(c0 + cc, 0);
      commit_x(1, Bu, Bv);
      bar_lds();
      if (cc + 3 < 8) ISSUE(c0 + cc + 3, Bu, Bv);
      gemm_chunk(c0 + cc + 1, 1);
      if (cc + 2 < 8) commit_x(0, Au, Av);
      bar_lds();
    }
  };
  auto do_xhalf = [&](int tt) {
    f4v z = {0.f, 0.f, 0.f, 0.f};
#pragma unroll
    for (int nt = 0; nt < 4; ++nt) acc[nt] = z;
    if (l == 0) {
      auto yi = [&](int cc, F4& u, F4& v) {
        const float* p = y + ((size_t)sb * T_ + tt) * P_ + ((cc & 7) << 5) + 8 * sg;
        u = *(const F4*)p;
        v = *(const F4*)(p + 4);
      };
      run_half(yi, 0);
    } else {
      const float* xp = hprv + (size_t)(tt & (WWIN - 1)) * HSLOT;
      auto xi = [&](int cc, F4& u, F4& v) { ring_issue(xp, cc, u, v); };
      run_half(xi, 0);
    }
  };

  // ---- prologue: x-half(0) ------------------------------------------------
  if (l > 0) { if (wait1(hflag + (l - 1) * 64, tid, 0, ABRT, -1)) return; }
  do_xhalf(0);

  const int cbase = w >> 1;              // own proj chunk (rotation start)

  for (int t = 0; t < T_; ++t) {
    if (*ABRT) return;

    // ---- h-half (recurrent critical path; k-tiles 8..15 = Whh) -----------
    if (t > 0) {
      if (wait1(hflag + l * 64, tid, t - 1, ABRT, w)) return;
      const float* hp = hsrc + (size_t)((t - 1) & (WWIN - 1)) * HSLOT;
      auto hi_ = [&](int cc, F4& u, F4& v) { ring_issue(hp, cc, u, v); };
      run_half(hi_, 8);
    }

    // ---- activations + cell update (D: col=lane&15, row=4*gq+reg) --------
#pragma unroll
    for (int nt = 0; nt < 4; ++nt) {
      float vi = acc[nt][0] + biasr[0];
      float vf = acc[nt][1] + biasr[1];
      float vg = acc[nt][2] + biasr[2];
      float vo = acc[nt][3] + biasr[3];
      float ig = fsig(vi), fg = fsig(vf), g2 = ftanh(vg), og = fsig(vo);
      float cn = fmaf(fg, cst[nt], ig * g2);
      cst[nt] = cn;
      ACTf[cellj * 64 + nt * 16 + lm] = og * ftanh(cn);
    }
    bar_lds();

    // ---- broadcast acts: LDS -> global [jq][b][4], dwordx2 agent stores --
    {
      float a0 = ACTf[(4 * jqr + 0) * 64 + b_r];
      float a1 = ACTf[(4 * jqr + 1) * 64 + b_r];
      float a2 = ACTf[(4 * jqr + 2) * 64 + b_r];
      float a3 = ACTf[(4 * jqr + 3) * 64 + b_r];
      float* dst = AGf + ((size_t)(4 * w + jqr) * 64 + b_r) * 4;
      sta2(dst + 0, a0, a1);
      sta2(dst + 2, a2, a3);
    }
    drain_vm();          // release: own stores complete at coherence point
    __syncthreads();     // all waves drained
    if (tid == 0)
      __hip_atomic_store(&pflag[l * 64 + w], t, __ATOMIC_RELAXED, __HIP_MEMORY_SCOPE_AGENT);

    // ---- projection: depth-4 ROLLED pipeline, progressive gated ----------
    int* pfl = pflag + l * 64;
    auto achunk = [&](int c) { return (cbase + c) & 31; };
    auto fld = [&](int p) {
      int idx = (2 * achunk(2 * p) + (lane & 3)) & 63;
      return (idx == w) ? 0x7fffffff
           : __hip_atomic_load(&pfl[idx], __ATOMIC_RELAXED, __HIP_MEMORY_SCOPE_AGENT);
    };
    auto fver = [&](int& fv, int p) {
      int it = 0;
      while (__ballot(fv < t) != 0ull) {
        if (++it > WDOG_CAP || *ABRT) { if (tid == 0) *ABRT = 1; break; }
        __builtin_amdgcn_s_sleep(2);
        fv = fld(p);
      }
      asm volatile("" ::: "memory");   // gated loads must not hoist above
    };
    auto proj_issue = [&](int ch, F4& lo, F4& hi, F4& wv) {
      const float* a0 = AGf + ((size_t)(8 * ch + 2 * jqr) * 64 + b_r) * 4;
      lda2(a0 + 0,   lo.f[0], lo.f[1]);
      lda2(a0 + 2,   lo.f[2], lo.f[3]);
      lda2(a0 + 256, hi.f[0], hi.f[1]);
      lda2(a0 + 258, hi.f[2], hi.f[3]);
      if (tid < 32)      // Whr is read-only input: plain cached load
        wv = *(const F4*)(Whr + ((size_t)(l * P_ + 4 * w + pws)) * H_
                          + 32 * ch + 4 * jqlw);
    };
    auto proj_commit = [&](int bufi, F4& lo, F4& hi, F4& wv) {
      float* ab = PRJ + bufi * PA_BUF;
      *(F4*)&ab[b_r * PA_CH + 8 * jqr]     = lo;
      *(F4*)&ab[b_r * PA_CH + 8 * jqr + 4] = hi;
      if (tid < 32)
        *(F4*)&(PRJ + PW_OFF + bufi * PW_BUF)[pws * PA_CH + 4 * jqlw] = wv;
    };
    float s = 0.f;
    auto proj_comp = [&](int bufi) {
      const float* ab = PRJ + bufi * PA_BUF + b_p * PA_CH;
      const float* wb = PRJ + PW_OFF + bufi * PW_BUF + pw * PA_CH;
#pragma unroll
      for (int jj = 0; jj < 8; ++jj) {
        F4 a  = *(const F4*)&ab[4 * jj];
        F4 wv = *(const F4*)&wb[4 * jj];
        s = fmaf(a.f[0], wv.f[0], s);
        s = fmaf(a.f[1], wv.f[1], s);
        s = fmaf(a.f[2], wv.f[2], s);
        s = fmaf(a.f[3], wv.f[3], s);
      }
    };

    {
      // prologue: verify pairs 0,1; issue chunks 0..3 (sets 0..3); stage 2,3
      int fvA = fld(0); fver(fvA, 0);
      int fvB = fld(1); fver(fvB, 1);
      F4 L0,H0,W0, L1,H1,W1, L2,H2,W2, L3,H3,W3;
      proj_issue(achunk(0), L0, H0, W0);
      proj_issue(achunk(1), L1, H1, W1);
      proj_issue(achunk(2), L2, H2, W2);
      proj_issue(achunk(3), L3, H3, W3);
      fvA = fld(2); fvB = fld(3);
      proj_commit(0, L0, H0, W0);
      bar_lds();
      // iteration j: lines for chunks 4j..4j+3; issue 4j+4..4j+7 (set k
      // refilled one line after its commit); verify pair 2j+2 before line 4j,
      // pair 2j+3 before line 4j+2; stage next-iter flags right after verify.
#pragma unroll 1
      for (int j = 0; j < 7; ++j) {
        const int c4 = 4 * j;
        fver(fvA, 2 * j + 2);
        int fvA2 = (j < 6) ? fld(2 * j + 4) : 0x7fffffff;
        proj_issue(achunk(c4 + 4), L0, H0, W0);
        proj_comp(0);
        proj_commit(1, L1, H1, W1);
        bar_lds();
        proj_issue(achunk(c4 + 5), L1, H1, W1);
        proj_comp(1);
        proj_commit(0, L2, H2, W2);
        bar_lds();
        fver(fvB, 2 * j + 3);
        int fvB2 = (j < 6) ? fld(2 * j + 5) : 0x7fffffff;
        proj_issue(achunk(c4 + 6), L2, H2, W2);
        proj_comp(0);
        proj_commit(1, L3, H3, W3);
        bar_lds();
        proj_issue(achunk(c4 + 7), L3, H3, W3);
        proj_comp(1);
        proj_commit(0, L0, H0, W0);
        bar_lds();
        fvA = fvA2; fvB = fvB2;
      }
      // epilogue: chunks 28..31 (sets hold 28..31; 28 already committed)
      proj_comp(0);
      proj_commit(1, L1, H1, W1);
      bar_lds();
      proj_comp(1);
      proj_commit(0, L2, H2, W2);
      bar_lds();
      proj_comp(0);
      proj_commit(1, L3, H3, W3);
      bar_lds();
      proj_comp(1);
    }

    // ---- emit h (ring [b][p], agent store) + output ----------------------
    if (l < 3) {                         // ring back-pressure
      if (wait1(hflag + (l + 1) * 64, tid, t - WWIN, ABRT, -1)) return;
    }
    sta(hsrc + (size_t)(t & (WWIN - 1)) * HSLOT + (size_t)b_p * P_ + (4 * w + pw), s);
    if (l == 3 && t >= msl)
      out[((size_t)b_p * (T_ - msl) + (t - msl)) * P_ + 4 * w + pw] = s;
    drain_vm();          // release h
    __syncthreads();
    if (tid == 0)
      __hip_atomic_store(&hflag[l * 64 + w], t, __ATOMIC_RELAXED, __HIP_MEMORY_SCOPE_AGENT);

    // ---- tail: x-half(t+1) off the critical cycle ------------------------
    if (t + 1 < T_) {
      if (l > 0) { if (wait1(hflag + (l - 1) * 64, tid, t + 1, ABRT, -1)) return; }
      do_xhalf(t + 1);
    }
  }
}

extern "C" void kernel_launch(void* const* d_in, const int* in_sizes, int n_in,
                              void* d_out, int out_size, void* d_ws, size_t ws_size,
                              hipStream_t stream) {
  const float* y   = (const float*)d_in[0];
  const float* Wih = (const float*)d_in[1];
  const float* Whh = (const float*)d_in[2];
  const float* bih = (const float*)d_in[3];
  const float* bhh = (const float*)d_in[4];
  const float* Whr = (const float*)d_in[5];
  const int*   msl = (const int*)d_in[6];
  float* out = (float*)d_out;

  // ws: [flags 4KB][act broadcast 1MB][h ring 2MB]  (~3 MB total)
  char*  ws    = (char*)d_ws;
  int*   flags = (int*)ws;
  float* actg  = (float*)(ws + 4096);
  float* hbuf  = (float*)(ws + 4096 + ACT_FLOATS * sizeof(float));

  hipMemsetAsync(flags, 0xFF, 4096, stream);   // epoch counters start at -1

  hipFuncSetAttribute(reinterpret_cast<const void*>(&lstm_persistent),
                      hipFuncAttributeMaxDynamicSharedMemorySize, LDS_BYTES);

  lstm_persistent<<<dim3(L_ * 64), dim3(NTHR), LDS_BYTES, stream>>>(
      y, Wih, Whh, bih, bhh, Whr, msl, out,
      hbuf, actg, flags /*hflag*/, flags + 256 /*pflag*/);
}

// Round 8
// 30192.874 us; speedup vs baseline: 10.3035x; 1.0252x over previous
//
#include <hip/hip_runtime.h>

// ============================================================================
// Persistent pipelined LSTM-with-projection, MI355X (gfx950).
//
// R15 vs R14 (31.0ms == R11; deeper proj prefetch bought nothing):
// proj's cost is NOT load latency (R14 falsified that) -- it is the LDS
// round-trip: 32 lines x {16 ds_read_b128 + 2-3 ds_write_b128 + bar_lds}
// ~= 5-9us/step of LDS-pipe + 33 barriers + 8-way-conflict commits
// (PA_CH=36 => stride = 4 mod 32). The round-trip existed only to remap act
// from load layout (jqr,b_r) to output layout (b_p,pw).
//
// Fix: PARTIAL-SUM proj, LDS-free. Thread (jqr,b_r) keeps its existing act
// load pattern (4 lda2/chunk) and accumulates part[p] for all 4 p over its
// own 8-j slice (32 FMA/chunk, same FLOPs). Whr read via plain loads --
// L1-resident (~16KB/WG) since all act/h traffic is agent-scope (L1-bypass).
// Zero proj LDS commits/reads, per-line barriers 33 -> 1 (final cross-wave
// reduction through the dead ACT region). Per-pair progressive gating and
// chunk rotation kept verbatim. XS now free during proj (future overlap).
// GEMM (R11 depth-2), tail x-half, watchdog, self-flag skip: unchanged.
// ============================================================================

#define B_    64
#define T_    1024
#define P_    256
#define H_    1024
#define L_    4
#define G4_   4096
#define NTHR  256
#define WWIN  8                     // h ring slots (power of two)
#define HSLOT (P_ * B_)             // 16384 floats per slot, layout [b][p]

// LDS (floats): WHI 16384 | WLO 16384 | XS 4096 | ACT 1024 | ABRT 4 = 37892
#define LDS_FLOATS 37892
#define LDS_BYTES  (LDS_FLOATS * 4)

#define ACT_FLOATS ((size_t)L_ * H_ * B_)        // 1 MB act broadcast bufs
#define WDOG_CAP 200000             // bounded polling before abort

struct alignas(16) F4 { float f[4]; };
typedef __attribute__((ext_vector_type(8))) short s8v;   // 8 bf16 (4 VGPRs)
typedef __attribute__((ext_vector_type(4))) float f4v;   // MFMA C/D

// ---- cross-WG data movement: compiler-tracked agent-scope accesses ---------
__device__ __forceinline__ void lda2(const float* p, float& a, float& b) {
  union { double d; float f[2]; } u;
  u.d = __hip_atomic_load((const double*)p, __ATOMIC_RELAXED,
                          __HIP_MEMORY_SCOPE_AGENT);
  a = u.f[0]; b = u.f[1];
}
__device__ __forceinline__ void sta2(float* p, float a, float b) {
  union { double d; float f[2]; } u;
  u.f[0] = a; u.f[1] = b;
  __hip_atomic_store((double*)p, u.d, __ATOMIC_RELAXED,
                     __HIP_MEMORY_SCOPE_AGENT);
}
__device__ __forceinline__ void sta(float* p, float v) {
  __hip_atomic_store(p, v, __ATOMIC_RELAXED, __HIP_MEMORY_SCOPE_AGENT);
}
__device__ __forceinline__ void drain_vm() {   // release: drain own stores
  asm volatile("s_waitcnt vmcnt(0)" ::: "memory");
}
// Hot-loop barrier: LDS visibility only -- does NOT drain vmcnt, so global
// prefetches survive. Compiler inserts vmcnt waits before each USE.
__device__ __forceinline__ void bar_lds() {
  asm volatile("s_waitcnt lgkmcnt(0)\n\ts_barrier" ::: "memory");
}

__device__ __forceinline__ float fsig(float x) {
  float e = __expf(-x);                        // saturation-safe
  return __builtin_amdgcn_rcpf(1.0f + e);
}
__device__ __forceinline__ float ftanh(float x) {
  float ax = fabsf(x);
  float e  = __expf(-2.0f * ax);               // in (0,1] -> no overflow/NaN
  float r  = (1.0f - e) * __builtin_amdgcn_rcpf(1.0f + e);
  return copysignf(r, x);
}
// ---- bf16 split helpers (round-to-nearest-even) ----------------------------
__device__ __forceinline__ ushort bf16_rne(float f) {
  uint u = __float_as_uint(f);
  uint r = u + 0x7FFFu + ((u >> 16) & 1u);
  return (ushort)(r >> 16);
}
__device__ __forceinline__ float bf16_to_f(ushort h) {
  return __uint_as_float(((uint)h) << 16);
}
// wave 0 polls 64 flags; others park at the barrier. Lane == self substitutes
// satisfied (own store precedes in program order). Returns nonzero on abort.
__device__ __forceinline__ int wait1(int* f, int tid, int target, int* abrt,
                                     int self) {
  if (tid < 64) {
    int it = 0;
    while (true) {
      int v = (tid == self) ? 0x7fffffff
            : __hip_atomic_load(&f[tid], __ATOMIC_RELAXED, __HIP_MEMORY_SCOPE_AGENT);
      if (__ballot(v < target) == 0ull) break;
      if (++it > WDOG_CAP || *abrt) { if (tid == 0) *abrt = 1; break; }
      __builtin_amdgcn_s_sleep(2);
    }
  }
  __syncthreads();
  asm volatile("" ::: "memory");   // no hoisting data loads above the wait
  return *abrt;                    // LDS, uniform across WG
}

extern "C" __global__ void __launch_bounds__(NTHR, 1)
lstm_persistent(const float* __restrict__ y,
                const float* __restrict__ Wih,
                const float* __restrict__ Whh,
                const float* __restrict__ bih,
                const float* __restrict__ bhh,
                const float* __restrict__ Whr,
                const int*   __restrict__ mslp,
                float*       __restrict__ out,
                float*       __restrict__ hbuf,
                float*       __restrict__ actg,
                int*         __restrict__ hflag,
                int*         __restrict__ pflag)
{
  extern __shared__ float lds[];
  ushort* WHI  = (ushort*)lds;          // frag-linear: [(kt*4+g)*64+m] x 8 bf16
  ushort* WLO  = WHI + 32768;
  ushort* XS   = WLO + 32768;           // 2 bufs x (256 hi + 256 lo) frags
  float*  ACTf = lds + 36864;           // [16 cells][64 b]; proj: RED buffer
  int*    ABRT = (int*)(lds + 37888);   // watchdog abort word

  const int bid = blockIdx.x;
  const int l   = (bid & 7) >> 1;       // layer on XCD pair {2l,2l+1}
  const int w   = ((bid & 1)) + 2 * (bid >> 3);   // 0..63, bijective
  const int J0  = w * 16;
  const int tid = threadIdx.x;
  const int msl = mslp[0];

  if (tid == 0) *ABRT = 0;

  // ---- one-time: gate weights -> bf16 (hi,lo) frag-linear LDS -------------
  {
    const float* wih_l = Wih + (size_t)l * G4_ * P_;
    const float* whh_l = Whh + (size_t)l * G4_ * P_;
    for (int e = tid; e < 4096; e += NTHR) {
      int m  = e & 63;
      int g  = (e >> 6) & 3;
      int kt = e >> 8;
      int grow = (m & 3) * H_ + J0 + (m >> 2);    // torch gate order i,f,g,o
      int k = kt * 32 + g * 8;
      const float* src = (k < 256) ? (wih_l + (size_t)grow * P_ + k)
                                   : (whh_l + (size_t)grow * P_ + (k - 256));
      F4 aa = *(const F4*)src;
      F4 bb = *(const F4*)(src + 4);
      float xs8[8] = {aa.f[0], aa.f[1], aa.f[2], aa.f[3],
                      bb.f[0], bb.f[1], bb.f[2], bb.f[3]};
      s8v h8, l8;
#pragma unroll
      for (int i = 0; i < 8; ++i) {
        ushort hi = bf16_rne(xs8[i]);
        ushort lo = bf16_rne(xs8[i] - bf16_to_f(hi));
        h8[i] = (short)hi; l8[i] = (short)lo;
      }
      ((s8v*)WHI)[e] = h8;
      ((s8v*)WLO)[e] = l8;
    }
  }
  __syncthreads();

  // ---- thread mappings ----------------------------------------------------
  const int w4   = tid >> 6;            // wave 0..3 = M-stripe (16 gate rows)
  const int lane = tid & 63;
  const int gq   = lane >> 4;           // k-group of A/B fragment
  const int lm   = lane & 15;           // A row-in-stripe / D column (b)
  const int aix  = 16 * w4 + lm;        // A fragment row index 0..63
  const int cellj = 4 * w4 + gq;        // my cell 0..15 (from D layout)
  // staging: thread -> (b, k-octet)
  const int sb = tid >> 2;              // b 0..63
  const int sg = tid & 3;               // k-group 0..3 (k0 = 8*sg)
  // act repack / proj accumulate:
  const int jqr = tid >> 6, b_r = tid & 63;
  // proj output / h emit:
  const int b_p = (w4 << 4) | (tid & 15);
  const int pw  = (tid >> 4) & 3;

  float* hsrc = hbuf + (size_t)l * (WWIN * HSLOT);
  const float* hprv = (l > 0) ? (hbuf + (size_t)(l - 1) * (WWIN * HSLOT)) : hbuf;
  float* AGf = actg + (size_t)l * H_ * B_;   // [jq 0..255][b 0..63] of 4 floats

  float biasr[4];
#pragma unroll
  for (int gg = 0; gg < 4; ++gg) {
    int grow = gg * H_ + J0 + cellj;
    biasr[gg] = bih[l * G4_ + grow] + bhh[l * G4_ + grow];
  }

  float cst[4] = {0.f, 0.f, 0.f, 0.f};       // c-state: my cell at 4 b's
  f4v acc[4];                                // gate accum, lives across tail

  // ---- GEMM machinery (R11 depth-2, known-good) ---------------------------
  auto gemm_chunk = [&](int kt, int par) {
    const s8v* WHIv = (const s8v*)WHI;
    const s8v* WLOv = (const s8v*)WLO;
    s8v ahi = WHIv[(kt * 4 + gq) * 64 + aix];
    s8v alo = WLOv[(kt * 4 + gq) * 64 + aix];
    const s8v* XB = (const s8v*)XS + par * 512;
    const int bbase = gq * 64 + lm;
#pragma unroll
    for (int nt = 0; nt < 4; ++nt) {
      s8v bhi = XB[bbase + nt * 16];
      s8v blo = XB[256 + bbase + nt * 16];
      acc[nt] = __builtin_amdgcn_mfma_f32_16x16x32_bf16(ahi, bhi, acc[nt], 0, 0, 0);
      acc[nt] = __builtin_amdgcn_mfma_f32_16x16x32_bf16(ahi, blo, acc[nt], 0, 0, 0);
      acc[nt] = __builtin_amdgcn_mfma_f32_16x16x32_bf16(alo, bhi, acc[nt], 0, 0, 0);
    }
  };
  auto ring_issue = [&](const float* src, int cc, F4& u, F4& v) {
    const float* p = src + (size_t)sb * P_ + ((cc & 7) << 5) + 8 * sg;
    lda2(p + 0, u.f[0], u.f[1]);
    lda2(p + 2, u.f[2], u.f[3]);
    lda2(p + 4, v.f[0], v.f[1]);
    lda2(p + 6, v.f[2], v.f[3]);
  };
  auto commit_x = [&](int par, const F4& u, const F4& v) {
    s8v h8, l8;
#pragma unroll
    for (int i = 0; i < 4; ++i) {
      ushort hu = bf16_rne(u.f[i]);
      ushort lu = bf16_rne(u.f[i] - bf16_to_f(hu));
      ushort hv = bf16_rne(v.f[i]);
      ushort lv = bf16_rne(v.f[i] - bf16_to_f(hv));
      h8[i]     = (short)hu; l8[i]     = (short)lu;
      h8[i + 4] = (short)hv; l8[i + 4] = (short)lv;
    }
    s8v* XB = (s8v*)XS + par * 512;
    XB[sg * 64 + sb]       = h8;
    XB[256 + sg * 64 + sb] = l8;
  };
  auto run_half = [&](auto&& ISSUE, int c0) {
    F4 Au, Av, Bu, Bv;
    ISSUE(c0 + 0, Au, Av);
    ISSUE(c0 + 1, Bu, Bv);
    commit_x(0, Au, Av);
    bar_lds();
#pragma unroll
    for (int cc = 0; cc < 8; cc += 2) {
      if (cc + 2 < 8) ISSUE(c0 + cc + 2, Au, Av);
      gemm_chunk(c0 + cc, 0);
      commit_x(1, Bu, Bv);
      bar_lds();
      if (cc + 3 < 8) ISSUE(c0 + cc + 3, Bu, Bv);
      gemm_chunk(c0 + cc + 1, 1);
      if (cc + 2 < 8) commit_x(0, Au, Av);
      bar_lds();
    }
  };
  auto do_xhalf = [&](int tt) {
    f4v z = {0.f, 0.f, 0.f, 0.f};
#pragma unroll
    for (int nt = 0; nt < 4; ++nt) acc[nt] = z;
    if (l == 0) {
      auto yi = [&](int cc, F4& u, F4& v) {
        const float* p = y + ((size_t)sb * T_ + tt) * P_ + ((cc & 7) << 5) + 8 * sg;
        u = *(const F4*)p;
        v = *(const F4*)(p + 4);
      };
      run_half(yi, 0);
    } else {
      const float* xp = hprv + (size_t)(tt & (WWIN - 1)) * HSLOT;
      auto xi = [&](int cc, F4& u, F4& v) { ring_issue(xp, cc, u, v); };
      run_half(xi, 0);
    }
  };

  // ---- prologue: x-half(0) ------------------------------------------------
  if (l > 0) { if (wait1(hflag + (l - 1) * 64, tid, 0, ABRT, -1)) return; }
  do_xhalf(0);

  const int cbase = w >> 1;              // own proj chunk (rotation start)
  const float* whrB = Whr + ((size_t)(l * P_ + 4 * w)) * H_;   // my 4 p-rows

  for (int t = 0; t < T_; ++t) {
    if (*ABRT) return;

    // ---- h-half (recurrent critical path; k-tiles 8..15 = Whh) -----------
    if (t > 0) {
      if (wait1(hflag + l * 64, tid, t - 1, ABRT, w)) return;
      const float* hp = hsrc + (size_t)((t - 1) & (WWIN - 1)) * HSLOT;
      auto hi_ = [&](int cc, F4& u, F4& v) { ring_issue(hp, cc, u, v); };
      run_half(hi_, 8);
    }

    // ---- activations + cell update (D: col=lane&15, row=4*gq+reg) --------
#pragma unroll
    for (int nt = 0; nt < 4; ++nt) {
      float vi = acc[nt][0] + biasr[0];
      float vf = acc[nt][1] + biasr[1];
      float vg = acc[nt][2] + biasr[2];
      float vo = acc[nt][3] + biasr[3];
      float ig = fsig(vi), fg = fsig(vf), g2 = ftanh(vg), og = fsig(vo);
      float cn = fmaf(fg, cst[nt], ig * g2);
      cst[nt] = cn;
      ACTf[cellj * 64 + nt * 16 + lm] = og * ftanh(cn);
    }
    bar_lds();

    // ---- broadcast acts: LDS -> global [jq][b][4], dwordx2 agent stores --
    {
      float a0 = ACTf[(4 * jqr + 0) * 64 + b_r];
      float a1 = ACTf[(4 * jqr + 1) * 64 + b_r];
      float a2 = ACTf[(4 * jqr + 2) * 64 + b_r];
      float a3 = ACTf[(4 * jqr + 3) * 64 + b_r];
      float* dst = AGf + ((size_t)(4 * w + jqr) * 64 + b_r) * 4;
      sta2(dst + 0, a0, a1);
      sta2(dst + 2, a2, a3);
    }
    drain_vm();          // release: own stores complete at coherence point
    __syncthreads();     // all waves drained (also: ACTf reads done -> RED ok)
    if (tid == 0)
      __hip_atomic_store(&pflag[l * 64 + w], t, __ATOMIC_RELAXED, __HIP_MEMORY_SCOPE_AGENT);

    // ---- projection: LDS-free partial sums, progressive gated ------------
    // Thread (jqr,b_r): per chunk load act[j][b_r] for its 8 j (4 lda2,
    // same pattern as before) + Whr[4w+p][j0..j0+7] (8 F4, L1-hot) and
    // accumulate part[p] (32 FMA). Depth-4 rolled pipeline, no LDS.
    int* pfl = pflag + l * 64;
    auto achunk = [&](int c) { return (cbase + c) & 31; };
    auto fld = [&](int p) {
      int idx = (2 * achunk(2 * p) + (lane & 3)) & 63;
      return (idx == w) ? 0x7fffffff
           : __hip_atomic_load(&pfl[idx], __ATOMIC_RELAXED, __HIP_MEMORY_SCOPE_AGENT);
    };
    auto fver = [&](int& fv, int p) {
      int it = 0;
      while (__ballot(fv < t) != 0ull) {
        if (++it > WDOG_CAP || *ABRT) { if (tid == 0) *ABRT = 1; break; }
        __builtin_amdgcn_s_sleep(2);
        fv = fld(p);
      }
      asm volatile("" ::: "memory");   // gated loads must not hoist above
    };

    F4 part;
    part.f[0] = 0.f; part.f[1] = 0.f; part.f[2] = 0.f; part.f[3] = 0.f;
    auto pissue = [&](int c, F4& lo, F4& hi) {
      const int ch = achunk(c);
      const float* a0 = AGf + ((size_t)(8 * ch + 2 * jqr) * 64 + b_r) * 4;
      lda2(a0 + 0,   lo.f[0], lo.f[1]);
      lda2(a0 + 2,   lo.f[2], lo.f[3]);
      lda2(a0 + 256, hi.f[0], hi.f[1]);
      lda2(a0 + 258, hi.f[2], hi.f[3]);
    };
    auto pcomp = [&](int c, F4& lo, F4& hi) {
      const int ch = achunk(c);
      const int j0 = 32 * ch + 8 * jqr;
#pragma unroll
      for (int p = 0; p < 4; ++p) {
        F4 wa = *(const F4*)(whrB + (size_t)p * H_ + j0);
        F4 wb = *(const F4*)(whrB + (size_t)p * H_ + j0 + 4);
        part.f[p] = fmaf(lo.f[0], wa.f[0], part.f[p]);
        part.f[p] = fmaf(lo.f[1], wa.f[1], part.f[p]);
        part.f[p] = fmaf(lo.f[2], wa.f[2], part.f[p]);
        part.f[p] = fmaf(lo.f[3], wa.f[3], part.f[p]);
        part.f[p] = fmaf(hi.f[0], wb.f[0], part.f[p]);
        part.f[p] = fmaf(hi.f[1], wb.f[1], part.f[p]);
        part.f[p] = fmaf(hi.f[2], wb.f[2], part.f[p]);
        part.f[p] = fmaf(hi.f[3], wb.f[3], part.f[p]);
      }
    };

    {
      // prologue: verify pairs 0,1 (own first); issue chunks 0..3; stage 2,3
      int fvA = fld(0); fver(fvA, 0);
      int fvB = fld(1); fver(fvB, 1);
      F4 A0l, A0h, A1l, A1h, A2l, A2h, A3l, A3h;
      pissue(0, A0l, A0h);
      pissue(1, A1l, A1h);
      pissue(2, A2l, A2h);
      pissue(3, A3l, A3h);
      fvA = fld(2); fvB = fld(3);
      // iteration j: compute chunks 4j..4j+3, issue 4j+4..4j+7 (depth-4);
      // verify pair 2j+2 before issues 4j+4/5, pair 2j+3 before 4j+6/7;
      // stage next-iter flags right after each verify.
#pragma unroll 1
      for (int j = 0; j < 7; ++j) {
        const int c4 = 4 * j;
        fver(fvA, 2 * j + 2);
        int fvA2 = (j < 6) ? fld(2 * j + 4) : 0x7fffffff;
        pcomp(c4 + 0, A0l, A0h); pissue(c4 + 4, A0l, A0h);
        pcomp(c4 + 1, A1l, A1h); pissue(c4 + 5, A1l, A1h);
        fver(fvB, 2 * j + 3);
        int fvB2 = (j < 6) ? fld(2 * j + 5) : 0x7fffffff;
        pcomp(c4 + 2, A2l, A2h); pissue(c4 + 6, A2l, A2h);
        pcomp(c4 + 3, A3l, A3h); pissue(c4 + 7, A3l, A3h);
        fvA = fvA2; fvB = fvB2;
      }
      // epilogue: chunks 28..31
      pcomp(28, A0l, A0h);
      pcomp(29, A1l, A1h);
      pcomp(30, A2l, A2h);
      pcomp(31, A3l, A3h);
    }

    // ---- cross-wave reduction: part[(jqr,b_r)][p] -> s at (b_p,pw) -------
    float s;
    {
      float* RED = ACTf;               // 1024 floats, dead since broadcast
      *(F4*)&RED[tid * 4] = part;
      bar_lds();
      s = RED[(0 * 64 + b_p) * 4 + pw] + RED[(1 * 64 + b_p) * 4 + pw]
        + RED[(2 * 64 + b_p) * 4 + pw] + RED[(3 * 64 + b_p) * 4 + pw];
    }

    // ---- emit h (ring [b][p], agent store) + output ----------------------
    if (l < 3) {                         // ring back-pressure
      if (wait1(hflag + (l + 1) * 64, tid, t - WWIN, ABRT, -1)) return;
    }
    sta(hsrc + (size_t)(t & (WWIN - 1)) * HSLOT + (size_t)b_p * P_ + (4 * w + pw), s);
    if (l == 3 && t >= msl)
      out[((size_t)b_p * (T_ - msl) + (t - msl)) * P_ + 4 * w + pw] = s;
    drain_vm();          // release h
    __syncthreads();     // also orders RED reads before next-iter ACTf writes
    if (tid == 0)
      __hip_atomic_store(&hflag[l * 64 + w], t, __ATOMIC_RELAXED, __HIP_MEMORY_SCOPE_AGENT);

    // ---- tail: x-half(t+1) off the critical cycle ------------------------
    if (t + 1 < T_) {
      if (l > 0) { if (wait1(hflag + (l - 1) * 64, tid, t + 1, ABRT, -1)) return; }
      do_xhalf(t + 1);
    }
  }
}

extern "C" void kernel_launch(void* const* d_in, const int* in_sizes, int n_in,
                              void* d_out, int out_size, void* d_ws, size_t ws_size,
                              hipStream_t stream) {
  const float* y   = (const float*)d_in[0];
  const float* Wih = (const float*)d_in[1];
  const float* Whh = (const float*)d_in[2];
  const float* bih = (const float*)d_in[3];
  const float* bhh = (const float*)d_in[4];
  const float* Whr = (const float*)d_in[5];
  const int*   msl = (const int*)d_in[6];
  float* out = (float*)d_out;

  // ws: [flags 4KB][act broadcast 1MB][h ring 2MB]  (~3 MB total)
  char*  ws    = (char*)d_ws;
  int*   flags = (int*)ws;
  float* actg  = (float*)(ws + 4096);
  float* hbuf  = (float*)(ws + 4096 + ACT_FLOATS * sizeof(float));

  hipMemsetAsync(flags, 0xFF, 4096, stream);   // epoch counters start at -1

  hipFuncSetAttribute(reinterpret_cast<const void*>(&lstm_persistent),
                      hipFuncAttributeMaxDynamicSharedMemorySize, LDS_BYTES);

  lstm_persistent<<<dim3(L_ * 64), dim3(NTHR), LDS_BYTES, stream>>>(
      y, Wih, Whh, bih, bhh, Whr, msl, out,
      hbuf, actg, flags /*hflag*/, flags + 256 /*pflag*/);
}